// Round 11
// baseline (695.625 us; speedup 1.0000x reference)
//
#include <hip/hip_runtime.h>

#define HH 768
#define SS 512
#define NB 2
#define NHEADS 12
#define KTOP 256
#define ETOT (NB*SS*KTOP)        // 262144
#define LN_EPS 1e-5f

// Output layout (floats): node_features [786432] | edge_index [524288] | edge_attr [201326592]
#define EI_OFF 786432L
#define EA_OFF 1310720L
#define PSZ    786432L           // one [1024][768] partial buffer

// 16-FMA outer-product micro-tile
#define FMA16(a,b) \
    acc[0][0]=fmaf(a.x,b.x,acc[0][0]); acc[0][1]=fmaf(a.x,b.y,acc[0][1]); \
    acc[0][2]=fmaf(a.x,b.z,acc[0][2]); acc[0][3]=fmaf(a.x,b.w,acc[0][3]); \
    acc[1][0]=fmaf(a.y,b.x,acc[1][0]); acc[1][1]=fmaf(a.y,b.y,acc[1][1]); \
    acc[1][2]=fmaf(a.y,b.z,acc[1][2]); acc[1][3]=fmaf(a.y,b.w,acc[1][3]); \
    acc[2][0]=fmaf(a.z,b.x,acc[2][0]); acc[2][1]=fmaf(a.z,b.y,acc[2][1]); \
    acc[2][2]=fmaf(a.z,b.z,acc[2][2]); acc[2][3]=fmaf(a.z,b.w,acc[2][3]); \
    acc[3][0]=fmaf(a.w,b.x,acc[3][0]); acc[3][1]=fmaf(a.w,b.y,acc[3][1]); \
    acc[3][2]=fmaf(a.w,b.z,acc[3][2]); acc[3][3]=fmaf(a.w,b.w,acc[3][3]);

// transpose-store one 64x4 column slab into LDS tile
#define STORE_TILE(DST, V0, V1) \
    (DST)[sc4*4+0][srow]    = (V0).x; (DST)[sc4*4+1][srow]    = (V0).y; \
    (DST)[sc4*4+2][srow]    = (V0).z; (DST)[sc4*4+3][srow]    = (V0).w; \
    (DST)[sc4*4+0][srow+32] = (V1).x; (DST)[sc4*4+1][srow+32] = (V1).y; \
    (DST)[sc4*4+2][srow+32] = (V1).z; (DST)[sc4*4+3][srow+32] = (V1).w;

__device__ __forceinline__ float4 f4sum(const float* __restrict__ p0,
                                        const float* __restrict__ p1,
                                        const float* __restrict__ b,
                                        long off, int bcol)
{
    const float4 x = *(const float4*)(p0 + off);
    const float4 y = *(const float4*)(p1 + off);
    const float4 z = *(const float4*)(b + bcol);
    float4 r;
    r.x = x.x + y.x + z.x; r.y = x.y + y.y + z.y;
    r.z = x.z + y.z + z.z; r.w = x.w + y.w + z.w;
    return r;
}

// ---------------------------------------------------------------------------
// proj1 split-K: P[kh] = hidden @ Wp^T over K-half kh. grid(12,16,2).
// Double-buffered (384 blocks — all resident regardless of LDS).
// ---------------------------------------------------------------------------
__global__ __launch_bounds__(256, 3) void gemm_sk1(
    const float* __restrict__ A, const float* __restrict__ W,
    float* __restrict__ P)
{
    __shared__ float As[2][32][68];
    __shared__ float Ws[2][32][68];
    const int tid = threadIdx.x;
    const int tm = tid >> 4, tn = tid & 15;
    const int m0 = blockIdx.y * 64, n0 = blockIdx.x * 64;
    const int kh = blockIdx.z;
    const int srow = tid >> 3, sc4 = tid & 7;
    const int kbeg = kh * 384;

    const float* Ar0 = A + (long)(m0 + srow) * HH + kbeg + sc4 * 4;
    const float* Ar1 = Ar0 + 32 * HH;
    const float* Wr0 = W + (long)(n0 + srow) * HH + kbeg + sc4 * 4;
    const float* Wr1 = Wr0 + 32 * HH;

    float4 pa0 = *(const float4*)Ar0, pa1 = *(const float4*)Ar1;
    float4 pw0 = *(const float4*)Wr0, pw1 = *(const float4*)Wr1;

    float acc[4][4] = {};
    for (int kt = 0; kt < 12; ++kt) {
        const int cur = kt & 1;
        STORE_TILE(As[cur], pa0, pa1);
        STORE_TILE(Ws[cur], pw0, pw1);
        __syncthreads();
        if (kt < 11) {
            const int off = (kt + 1) * 32;
            pa0 = *(const float4*)(Ar0 + off);
            pa1 = *(const float4*)(Ar1 + off);
            pw0 = *(const float4*)(Wr0 + off);
            pw1 = *(const float4*)(Wr1 + off);
        }
        #pragma unroll
        for (int k = 0; k < 32; ++k) {
            const float4 a = *(const float4*)&As[cur][k][tm*4];
            const float4 b = *(const float4*)&Ws[cur][k][tn*4];
            FMA16(a, b)
        }
    }

    float* C = P + (long)kh * PSZ + (long)m0 * HH + n0;
    #pragma unroll
    for (int i = 0; i < 4; ++i) {
        float4 r;
        r.x = acc[i][0]; r.y = acc[i][1]; r.z = acc[i][2]; r.w = acc[i][3];
        *(float4*)(C + (long)(tm*4 + i) * HH + tn * 4) = r;
    }
}

// ---------------------------------------------------------------------------
// proj2 split-K: QKP[sel][kh] = (p0+p1+bp) @ W(sel)^T. grid(12,16,5):
// z 0..3 = GEMM planes, z == 4 = folded LayerNorm (192 blocks, grid-stride).
// SINGLE-buffered LDS (34.8 KB) -> all 960 blocks resident in one generation.
// ---------------------------------------------------------------------------
__global__ __launch_bounds__(256, 4) void gemm_sk2(
    const float* __restrict__ P, const float* __restrict__ bp,
    const float* __restrict__ Wq, const float* __restrict__ Wk,
    float* __restrict__ QKP,
    const float* __restrict__ gamma, const float* __restrict__ beta,
    float* __restrict__ lnout)
{
    __shared__ float As[32][68];
    __shared__ float Ws[32][68];
    __shared__ float rs_[4], rq_[4];
    const int tid = threadIdx.x;

    if (blockIdx.z == 4) {
        // ----- folded LayerNorm: node = p0 + p1 + bp -----
        const int fb = blockIdx.y * 12 + blockIdx.x;   // 0..191
        const int t  = tid;
        for (int row = fb; row < NB * SS; row += 192) {
            const float* x0 = P + (long)row * HH;
            const float* x1 = x0 + PSZ;
            const float v0 = x0[t]       + x1[t]       + bp[t];
            const float v1 = x0[t + 256] + x1[t + 256] + bp[t + 256];
            const float v2 = x0[t + 512] + x1[t + 512] + bp[t + 512];
            float s  = v0 + v1 + v2;
            float sq = v0 * v0 + v1 * v1 + v2 * v2;
            #pragma unroll
            for (int o = 32; o >= 1; o >>= 1) {
                s  += __shfl_xor(s, o);
                sq += __shfl_xor(sq, o);
            }
            if ((t & 63) == 0) { rs_[t >> 6] = s; rq_[t >> 6] = sq; }
            __syncthreads();
            const float S = rs_[0] + rs_[1] + rs_[2] + rs_[3];
            const float Q = rq_[0] + rq_[1] + rq_[2] + rq_[3];
            const float mu  = S * (1.f / HH);
            const float var = Q * (1.f / HH) - mu * mu;
            const float inv = rsqrtf(var + LN_EPS);
            float* o = lnout + (long)row * HH;
            o[t]       = (v0 - mu) * inv * gamma[t]       + beta[t];
            o[t + 256] = (v1 - mu) * inv * gamma[t + 256] + beta[t + 256];
            o[t + 512] = (v2 - mu) * inv * gamma[t + 512] + beta[t + 512];
            __syncthreads();   // before rs_/rq_ reuse
        }
        return;
    }

    const int tm = tid >> 4, tn = tid & 15;
    const int m0 = blockIdx.y * 64, n0 = blockIdx.x * 64;
    const int sel = blockIdx.z >> 1, kh = blockIdx.z & 1;
    const float* W = sel ? Wk : Wq;
    const int srow = tid >> 3, sc4 = tid & 7;
    const int kbeg = kh * 384;

    const float* P1 = P + PSZ;
    const long aoff0 = (long)(m0 + srow) * HH + kbeg + sc4 * 4;
    const long aoff1 = aoff0 + 32 * HH;
    const int  bcol  = kbeg + sc4 * 4;
    const float* Wr0 = W + (long)(n0 + srow) * HH + kbeg + sc4 * 4;
    const float* Wr1 = Wr0 + 32 * HH;

    float4 pa0 = f4sum(P, P1, bp, aoff0, bcol);
    float4 pa1 = f4sum(P, P1, bp, aoff1, bcol);
    float4 pw0 = *(const float4*)Wr0;
    float4 pw1 = *(const float4*)Wr1;

    float acc[4][4] = {};
    for (int kt = 0; kt < 12; ++kt) {
        STORE_TILE(As, pa0, pa1);
        STORE_TILE(Ws, pw0, pw1);
        __syncthreads();
        if (kt < 11) {
            const int off = (kt + 1) * 32;
            pa0 = f4sum(P, P1, bp, aoff0 + off, bcol + off);
            pa1 = f4sum(P, P1, bp, aoff1 + off, bcol + off);
            pw0 = *(const float4*)(Wr0 + off);
            pw1 = *(const float4*)(Wr1 + off);
        }
        #pragma unroll
        for (int k = 0; k < 32; ++k) {
            const float4 a = *(const float4*)&As[k][tm*4];
            const float4 b = *(const float4*)&Ws[k][tn*4];
            FMA16(a, b)
        }
        if (kt < 11) __syncthreads();   // reads done before next overwrite
    }

    float* C = QKP + ((long)sel * 2 + kh) * PSZ + (long)m0 * HH + n0;
    #pragma unroll
    for (int i = 0; i < 4; ++i) {
        float4 r;
        r.x = acc[i][0]; r.y = acc[i][1]; r.z = acc[i][2]; r.w = acc[i][3];
        *(float4*)(C + (long)(tm*4 + i) * HH + tn * 4) = r;
    }
}

// ---------------------------------------------------------------------------
// QK^T: logits[z] = ((q0+q1+bq) @ (k0+k1+bk)^T)/8. grid(8,8,24).
// SINGLE-buffered LDS -> 4+ blocks/CU, 1536 blocks in ~1.5 generations.
// ---------------------------------------------------------------------------
__global__ __launch_bounds__(256, 4) void gemm_qk2(
    const float* __restrict__ QKP, const float* __restrict__ bq,
    const float* __restrict__ bk, float* __restrict__ logits)
{
    __shared__ float As[32][68];
    __shared__ float Ws[32][68];
    const int tid = threadIdx.x;
    const int tm = tid >> 4, tn = tid & 15;
    const int m0 = blockIdx.y * 64, n0 = blockIdx.x * 64;
    const int z = blockIdx.z, bz = z / NHEADS, hz = z - bz * NHEADS;
    const int srow = tid >> 3, sc4 = tid & 7;

    const float* q0 = QKP;
    const float* q1 = QKP + PSZ;
    const float* k0 = QKP + 2 * PSZ;
    const float* k1 = QKP + 3 * PSZ;

    const long rbase = (long)bz * SS * HH + hz * 64;
    const long aoff0 = rbase + (long)(m0 + srow) * HH + sc4 * 4;
    const long aoff1 = aoff0 + 32 * HH;
    const long woff0 = rbase + (long)(n0 + srow) * HH + sc4 * 4;
    const long woff1 = woff0 + 32 * HH;
    const int  bcol  = hz * 64 + sc4 * 4;

    float4 pa0 = f4sum(q0, q1, bq, aoff0, bcol);
    float4 pa1 = f4sum(q0, q1, bq, aoff1, bcol);
    float4 pw0 = f4sum(k0, k1, bk, woff0, bcol);
    float4 pw1 = f4sum(k0, k1, bk, woff1, bcol);

    float acc[4][4] = {};
    for (int kt = 0; kt < 2; ++kt) {
        STORE_TILE(As, pa0, pa1);
        STORE_TILE(Ws, pw0, pw1);
        __syncthreads();
        if (kt == 0) {
            pa0 = f4sum(q0, q1, bq, aoff0 + 32, bcol + 32);
            pa1 = f4sum(q0, q1, bq, aoff1 + 32, bcol + 32);
            pw0 = f4sum(k0, k1, bk, woff0 + 32, bcol + 32);
            pw1 = f4sum(k0, k1, bk, woff1 + 32, bcol + 32);
        }
        #pragma unroll
        for (int k = 0; k < 32; ++k) {
            const float4 a = *(const float4*)&As[k][tm*4];
            const float4 b = *(const float4*)&Ws[k][tn*4];
            FMA16(a, b)
        }
        if (kt == 0) __syncthreads();
    }

    float* C = logits + (long)z * SS * SS;
    #pragma unroll
    for (int i = 0; i < 4; ++i) {
        float4 r;
        r.x = acc[i][0] * 0.125f;
        r.y = acc[i][1] * 0.125f;
        r.z = acc[i][2] * 0.125f;
        r.w = acc[i][3] * 0.125f;
        *(float4*)(C + (long)(m0 + tm*4 + i) * SS + n0 + tn * 4) = r;
    }
}

// ---------------------------------------------------------------------------
// FUSED attn_post + edge_attr (R8-proven version, single row per block):
//  - no max-subtraction (|logit| <~ 1; masked -1e9 underflows exp to 0.0)
//  - all 12 head-sums shuffle-reduced into red[12][4], ONE barrier
//  - We/be staged to LDS at block start
//  - packed 64-bit (value,index) keys for the exact top-k rank
// ---------------------------------------------------------------------------
__global__ __launch_bounds__(256) void attn_edge(
    const float* __restrict__ logits,  // [B][NHEADS][SS][SS]
    const int*   __restrict__ mask,    // [B][SS]
    const float* __restrict__ We, const float* __restrict__ be,
    float* __restrict__ ei,            // [2][ETOT] (float-encoded ints)
    float* __restrict__ ea)            // [ETOT][HH]
{
    const int row = blockIdx.x;        // 0..1023
    const int b   = row >> 9;
    const int qi  = row & 511;
    const int t   = threadIdx.x;
    const int wid = t >> 6, lane = t & 63;

    __shared__ float red[NHEADS][4];
    __shared__ unsigned long long keys[SS];   // 4 KB
    __shared__ float4 wt[192], bt[192];       // 6 KB
    __shared__ unsigned long long mskS[8];
    __shared__ float ssel[KTOP];              // 1 KB

    // stage We col 0 / be early; consumed only after barriers B2/B3
    if (t < 192) {
        float4 w;
        w.x = We[(long)(4 * t + 0) * HH];
        w.y = We[(long)(4 * t + 1) * HH];
        w.z = We[(long)(4 * t + 2) * HH];
        w.w = We[(long)(4 * t + 3) * HH];
        wt[t] = w;
        bt[t] = *(const float4*)(be + 4 * t);
    }

    const bool m0 = mask[b * SS + t] != 0;
    const bool m1 = mask[b * SS + t + 256] != 0;

    const float* basep = logits + ((long)b * NHEADS * SS + qi) * SS;

    // single-pass softmax sums, all heads, one barrier
    float x0[NHEADS], x1[NHEADS];
    #pragma unroll
    for (int h = 0; h < NHEADS; ++h) {
        const float* lr = basep + (long)h * SS * SS;
        const float l0 = m0 ? lr[t]       : -1e9f;
        const float l1 = m1 ? lr[t + 256] : -1e9f;
        x0[h] = __expf(l0);               // exp(-1e9) underflows to 0
        x1[h] = __expf(l1);
        float s = x0[h] + x1[h];
        #pragma unroll
        for (int o = 32; o >= 1; o >>= 1) s += __shfl_xor(s, o);
        if (lane == 0) red[h][wid] = s;
    }
    __syncthreads();                                       // B1

    float a0 = 0.f, a1 = 0.f;
    #pragma unroll
    for (int h = 0; h < NHEADS; ++h) {
        const float rs = 1.0f / (red[h][0] + red[h][1] + red[h][2] + red[h][3]);
        a0 = fmaf(x0[h], rs, a0);
        a1 = fmaf(x1[h], rs, a1);
    }
    a0 *= (1.f / NHEADS);
    a1 *= (1.f / NHEADS);

    // packed keys: (value bits << 32) | (SS-1-j)  => desc value, asc index
    const unsigned long long k0 =
        ((unsigned long long)__float_as_uint(a0) << 32) | (unsigned)(SS - 1 - t);
    const unsigned long long k1 =
        ((unsigned long long)__float_as_uint(a1) << 32) | (unsigned)(SS - 1 - (t + 256));
    keys[t]       = k0;
    keys[t + 256] = k1;
    __syncthreads();                                       // B2

    int r0 = 0, r1 = 0;
    #pragma unroll 8
    for (int j = 0; j < SS; ++j) {
        const unsigned long long kj = keys[j];
        r0 += (kj > k0);
        r1 += (kj > k1);
    }
    const bool sel0 = (r0 < KTOP);
    const bool sel1 = (r1 < KTOP);

    const unsigned long long mm0 = __ballot(sel0);
    const unsigned long long mm1 = __ballot(sel1);
    if (lane == 0) { mskS[wid] = mm0; mskS[4 + wid] = mm1; }
    __syncthreads();                                       // B3
    int cum[8]; int acc = 0;
    #pragma unroll
    for (int i = 0; i < 8; ++i) { cum[i] = acc; acc += __popcll(mskS[i]); }
    const unsigned long long lt = lane ? ((1ull << lane) - 1ull) : 0ull;
    const int p0 = cum[wid]     + __popcll(mskS[wid]     & lt);
    const int p1 = cum[4 + wid] + __popcll(mskS[4 + wid] & lt);

    const float srcv = (float)(b * SS + qi);
    const long  base_e = (long)row * KTOP;
    if (sel0) {
        ei[base_e + p0]        = srcv;
        ei[ETOT + base_e + p0] = (float)(b * SS + t);
        ssel[p0]               = a0;
    }
    if (sel1) {
        ei[base_e + p1]        = srcv;
        ei[ETOT + base_e + p1] = (float)(b * SS + t + 256);
        ssel[p1]               = a1;
    }
    __syncthreads();                                       // B4

    const int cA = t % 192, cB = (t + 64) % 192, cC = (t + 128) % 192;
    const float4 wA = wt[cA], bA = bt[cA];
    const float4 wB = wt[cB], bB = bt[cB];
    const float4 wC = wt[cC], bC = bt[cC];

    // stream this row's edge_attr slab: 256 edges x 768 floats = 49152 float4
    float4* dst = (float4*)(ea + base_e * HH);
    for (int m = 0; m < 64; ++m) {
        const int e_lo = m * 4;
        {
            const int e = e_lo + (t >= 192 ? 1 : 0);
            const float s = ssel[e];
            float4 r;
            r.x = fmaf(s, wA.x, bA.x); r.y = fmaf(s, wA.y, bA.y);
            r.z = fmaf(s, wA.z, bA.z); r.w = fmaf(s, wA.w, bA.w);
            dst[(3*m + 0) * 256 + t] = r;
        }
        {
            const int e = e_lo + 1 + (t >= 128 ? 1 : 0);
            const float s = ssel[e];
            float4 r;
            r.x = fmaf(s, wB.x, bB.x); r.y = fmaf(s, wB.y, bB.y);
            r.z = fmaf(s, wB.z, bB.z); r.w = fmaf(s, wB.w, bB.w);
            dst[(3*m + 1) * 256 + t] = r;
        }
        {
            const int e = e_lo + 2 + (t >= 64 ? 1 : 0);
            const float s = ssel[e];
            float4 r;
            r.x = fmaf(s, wC.x, bC.x); r.y = fmaf(s, wC.y, bC.y);
            r.z = fmaf(s, wC.z, bC.z); r.w = fmaf(s, wC.w, bC.w);
            dst[(3*m + 2) * 256 + t] = r;
        }
    }
}

extern "C" void kernel_launch(void* const* d_in, const int* in_sizes, int n_in,
                              void* d_out, int out_size, void* d_ws, size_t ws_size,
                              hipStream_t stream)
{
    const float* hidden = (const float*)d_in[0];
    const int*   mask   = (const int*)  d_in[1];
    const float* Wp = (const float*)d_in[2];
    const float* bp = (const float*)d_in[3];
    const float* Wq = (const float*)d_in[4];
    const float* bq = (const float*)d_in[5];
    const float* Wk = (const float*)d_in[6];
    const float* bk = (const float*)d_in[7];
    const float* We = (const float*)d_in[8];
    const float* be = (const float*)d_in[9];
    const float* gamma = (const float*)d_in[10];
    const float* beta  = (const float*)d_in[11];

    float* out = (float*)d_out;
    float* ws  = (float*)d_ws;

    float* logits = ws;                     // 6291456 floats (25.2 MB, proven fits)
    float* pn     = out + EA_OFF;           // proj1 partials [2][1024][768]
    float* qkp    = out + EA_OFF + 2*PSZ;   // q/k partials [4][1024][768]

    const dim3 blk(256);

    gemm_sk1<<<dim3(12, 16, 2), blk, 0, stream>>>(hidden, Wp, pn);
    // z 0..3: q/k partial GEMMs; z == 4: folded LayerNorm
    gemm_sk2<<<dim3(12, 16, 5), blk, 0, stream>>>(pn, bp, Wq, Wk, qkp,
                                                  gamma, beta, out);
    gemm_qk2<<<dim3(8, 8, NB * NHEADS), blk, 0, stream>>>(qkp, bq, bk, logits);
    attn_edge<<<dim3(NB * SS), blk, 0, stream>>>(logits, mask, We, be,
                                                 out + EI_OFF, out + EA_OFF);
}

// Round 12
// 245.264 us; speedup vs baseline: 2.8362x; 2.8362x over previous
//
#include <hip/hip_runtime.h>

#define HH 768
#define SS 512
#define NB 2
#define NHEADS 12
#define KTOP 256
#define ETOT (NB*SS*KTOP)        // 262144
#define LN_EPS 1e-5f

// Output layout (floats): node_features [786432] | edge_index [524288] | edge_attr [201326592]
#define EI_OFF 786432L
#define EA_OFF 1310720L
#define PSZ    786432L           // one [1024][768] partial buffer

// 16-FMA outer-product micro-tile
#define FMA16(a,b) \
    acc[0][0]=fmaf(a.x,b.x,acc[0][0]); acc[0][1]=fmaf(a.x,b.y,acc[0][1]); \
    acc[0][2]=fmaf(a.x,b.z,acc[0][2]); acc[0][3]=fmaf(a.x,b.w,acc[0][3]); \
    acc[1][0]=fmaf(a.y,b.x,acc[1][0]); acc[1][1]=fmaf(a.y,b.y,acc[1][1]); \
    acc[1][2]=fmaf(a.y,b.z,acc[1][2]); acc[1][3]=fmaf(a.y,b.w,acc[1][3]); \
    acc[2][0]=fmaf(a.z,b.x,acc[2][0]); acc[2][1]=fmaf(a.z,b.y,acc[2][1]); \
    acc[2][2]=fmaf(a.z,b.z,acc[2][2]); acc[2][3]=fmaf(a.z,b.w,acc[2][3]); \
    acc[3][0]=fmaf(a.w,b.x,acc[3][0]); acc[3][1]=fmaf(a.w,b.y,acc[3][1]); \
    acc[3][2]=fmaf(a.w,b.z,acc[3][2]); acc[3][3]=fmaf(a.w,b.w,acc[3][3]);

// transpose-store one 64x4 column slab into LDS tile
#define STORE_TILE(DST, V0, V1) \
    (DST)[sc4*4+0][srow]    = (V0).x; (DST)[sc4*4+1][srow]    = (V0).y; \
    (DST)[sc4*4+2][srow]    = (V0).z; (DST)[sc4*4+3][srow]    = (V0).w; \
    (DST)[sc4*4+0][srow+32] = (V1).x; (DST)[sc4*4+1][srow+32] = (V1).y; \
    (DST)[sc4*4+2][srow+32] = (V1).z; (DST)[sc4*4+3][srow+32] = (V1).w;

__device__ __forceinline__ float4 f4sum(const float* __restrict__ p0,
                                        const float* __restrict__ p1,
                                        const float* __restrict__ b,
                                        long off, int bcol)
{
    const float4 x = *(const float4*)(p0 + off);
    const float4 y = *(const float4*)(p1 + off);
    const float4 z = *(const float4*)(b + bcol);
    float4 r;
    r.x = x.x + y.x + z.x; r.y = x.y + y.y + z.y;
    r.z = x.z + y.z + z.z; r.w = x.w + y.w + z.w;
    return r;
}

// ---------------------------------------------------------------------------
// proj1 split-K: P[kh] = hidden @ Wp^T over K-half kh. grid(12,16,2).
// Double-buffered, launch_bounds(256,3) — R8-proven (no spills).
// ---------------------------------------------------------------------------
__global__ __launch_bounds__(256, 3) void gemm_sk1(
    const float* __restrict__ A, const float* __restrict__ W,
    float* __restrict__ P)
{
    __shared__ float As[2][32][68];
    __shared__ float Ws[2][32][68];
    const int tid = threadIdx.x;
    const int tm = tid >> 4, tn = tid & 15;
    const int m0 = blockIdx.y * 64, n0 = blockIdx.x * 64;
    const int kh = blockIdx.z;
    const int srow = tid >> 3, sc4 = tid & 7;
    const int kbeg = kh * 384;

    const float* Ar0 = A + (long)(m0 + srow) * HH + kbeg + sc4 * 4;
    const float* Ar1 = Ar0 + 32 * HH;
    const float* Wr0 = W + (long)(n0 + srow) * HH + kbeg + sc4 * 4;
    const float* Wr1 = Wr0 + 32 * HH;

    float4 pa0 = *(const float4*)Ar0, pa1 = *(const float4*)Ar1;
    float4 pw0 = *(const float4*)Wr0, pw1 = *(const float4*)Wr1;

    float acc[4][4] = {};
    for (int kt = 0; kt < 12; ++kt) {
        const int cur = kt & 1;
        STORE_TILE(As[cur], pa0, pa1);
        STORE_TILE(Ws[cur], pw0, pw1);
        __syncthreads();
        if (kt < 11) {
            const int off = (kt + 1) * 32;
            pa0 = *(const float4*)(Ar0 + off);
            pa1 = *(const float4*)(Ar1 + off);
            pw0 = *(const float4*)(Wr0 + off);
            pw1 = *(const float4*)(Wr1 + off);
        }
        #pragma unroll
        for (int k = 0; k < 32; ++k) {
            const float4 a = *(const float4*)&As[cur][k][tm*4];
            const float4 b = *(const float4*)&Ws[cur][k][tn*4];
            FMA16(a, b)
        }
    }

    float* C = P + (long)kh * PSZ + (long)m0 * HH + n0;
    #pragma unroll
    for (int i = 0; i < 4; ++i) {
        float4 r;
        r.x = acc[i][0]; r.y = acc[i][1]; r.z = acc[i][2]; r.w = acc[i][3];
        *(float4*)(C + (long)(tm*4 + i) * HH + tn * 4) = r;
    }
}

// ---------------------------------------------------------------------------
// proj2 split-K: QKP[sel][kh] = (p0+p1+bp) @ W(sel)^T. grid(12,16,5):
// z 0..3 = GEMM planes, z == 4 = folded LayerNorm (192 blocks, grid-stride).
// Double-buffered, launch_bounds(256,3) — R8-proven (R11's (256,4) spilled).
// ---------------------------------------------------------------------------
__global__ __launch_bounds__(256, 3) void gemm_sk2(
    const float* __restrict__ P, const float* __restrict__ bp,
    const float* __restrict__ Wq, const float* __restrict__ Wk,
    float* __restrict__ QKP,
    const float* __restrict__ gamma, const float* __restrict__ beta,
    float* __restrict__ lnout)
{
    __shared__ float As[2][32][68];
    __shared__ float Ws[2][32][68];
    __shared__ float rs_[4], rq_[4];
    const int tid = threadIdx.x;

    if (blockIdx.z == 4) {
        // ----- folded LayerNorm: node = p0 + p1 + bp -----
        const int fb = blockIdx.y * 12 + blockIdx.x;   // 0..191
        const int t  = tid;
        for (int row = fb; row < NB * SS; row += 192) {
            const float* x0 = P + (long)row * HH;
            const float* x1 = x0 + PSZ;
            const float v0 = x0[t]       + x1[t]       + bp[t];
            const float v1 = x0[t + 256] + x1[t + 256] + bp[t + 256];
            const float v2 = x0[t + 512] + x1[t + 512] + bp[t + 512];
            float s  = v0 + v1 + v2;
            float sq = v0 * v0 + v1 * v1 + v2 * v2;
            #pragma unroll
            for (int o = 32; o >= 1; o >>= 1) {
                s  += __shfl_xor(s, o);
                sq += __shfl_xor(sq, o);
            }
            if ((t & 63) == 0) { rs_[t >> 6] = s; rq_[t >> 6] = sq; }
            __syncthreads();
            const float S = rs_[0] + rs_[1] + rs_[2] + rs_[3];
            const float Q = rq_[0] + rq_[1] + rq_[2] + rq_[3];
            const float mu  = S * (1.f / HH);
            const float var = Q * (1.f / HH) - mu * mu;
            const float inv = rsqrtf(var + LN_EPS);
            float* o = lnout + (long)row * HH;
            o[t]       = (v0 - mu) * inv * gamma[t]       + beta[t];
            o[t + 256] = (v1 - mu) * inv * gamma[t + 256] + beta[t + 256];
            o[t + 512] = (v2 - mu) * inv * gamma[t + 512] + beta[t + 512];
            __syncthreads();   // before rs_/rq_ reuse
        }
        return;
    }

    const int tm = tid >> 4, tn = tid & 15;
    const int m0 = blockIdx.y * 64, n0 = blockIdx.x * 64;
    const int sel = blockIdx.z >> 1, kh = blockIdx.z & 1;
    const float* W = sel ? Wk : Wq;
    const int srow = tid >> 3, sc4 = tid & 7;
    const int kbeg = kh * 384;

    const float* P1 = P + PSZ;
    const long aoff0 = (long)(m0 + srow) * HH + kbeg + sc4 * 4;
    const long aoff1 = aoff0 + 32 * HH;
    const int  bcol  = kbeg + sc4 * 4;
    const float* Wr0 = W + (long)(n0 + srow) * HH + kbeg + sc4 * 4;
    const float* Wr1 = Wr0 + 32 * HH;

    float4 pa0 = f4sum(P, P1, bp, aoff0, bcol);
    float4 pa1 = f4sum(P, P1, bp, aoff1, bcol);
    float4 pw0 = *(const float4*)Wr0;
    float4 pw1 = *(const float4*)Wr1;

    float acc[4][4] = {};
    for (int kt = 0; kt < 12; ++kt) {
        const int cur = kt & 1;
        STORE_TILE(As[cur], pa0, pa1);
        STORE_TILE(Ws[cur], pw0, pw1);
        __syncthreads();
        if (kt < 11) {
            const int off = (kt + 1) * 32;
            pa0 = f4sum(P, P1, bp, aoff0 + off, bcol + off);
            pa1 = f4sum(P, P1, bp, aoff1 + off, bcol + off);
            pw0 = *(const float4*)(Wr0 + off);
            pw1 = *(const float4*)(Wr1 + off);
        }
        #pragma unroll
        for (int k = 0; k < 32; ++k) {
            const float4 a = *(const float4*)&As[cur][k][tm*4];
            const float4 b = *(const float4*)&Ws[cur][k][tn*4];
            FMA16(a, b)
        }
    }

    float* C = QKP + ((long)sel * 2 + kh) * PSZ + (long)m0 * HH + n0;
    #pragma unroll
    for (int i = 0; i < 4; ++i) {
        float4 r;
        r.x = acc[i][0]; r.y = acc[i][1]; r.z = acc[i][2]; r.w = acc[i][3];
        *(float4*)(C + (long)(tm*4 + i) * HH + tn * 4) = r;
    }
}

// ---------------------------------------------------------------------------
// QK^T: logits[z] = ((q0+q1+bq) @ (k0+k1+bk)^T)/8. grid(8,8,24).
// Double-buffered, launch_bounds(256,3) — R8-proven.
// ---------------------------------------------------------------------------
__global__ __launch_bounds__(256, 3) void gemm_qk2(
    const float* __restrict__ QKP, const float* __restrict__ bq,
    const float* __restrict__ bk, float* __restrict__ logits)
{
    __shared__ float As[2][32][68];
    __shared__ float Ws[2][32][68];
    const int tid = threadIdx.x;
    const int tm = tid >> 4, tn = tid & 15;
    const int m0 = blockIdx.y * 64, n0 = blockIdx.x * 64;
    const int z = blockIdx.z, bz = z / NHEADS, hz = z - bz * NHEADS;
    const int srow = tid >> 3, sc4 = tid & 7;

    const float* q0 = QKP;
    const float* q1 = QKP + PSZ;
    const float* k0 = QKP + 2 * PSZ;
    const float* k1 = QKP + 3 * PSZ;

    const long rbase = (long)bz * SS * HH + hz * 64;
    const long aoff0 = rbase + (long)(m0 + srow) * HH + sc4 * 4;
    const long aoff1 = aoff0 + 32 * HH;
    const long woff0 = rbase + (long)(n0 + srow) * HH + sc4 * 4;
    const long woff1 = woff0 + 32 * HH;
    const int  bcol  = hz * 64 + sc4 * 4;

    float4 pa0 = f4sum(q0, q1, bq, aoff0, bcol);
    float4 pa1 = f4sum(q0, q1, bq, aoff1, bcol);
    float4 pw0 = f4sum(k0, k1, bk, woff0, bcol);
    float4 pw1 = f4sum(k0, k1, bk, woff1, bcol);

    float acc[4][4] = {};
    for (int kt = 0; kt < 2; ++kt) {
        const int cur = kt & 1;
        STORE_TILE(As[cur], pa0, pa1);
        STORE_TILE(Ws[cur], pw0, pw1);
        __syncthreads();
        if (kt == 0) {
            pa0 = f4sum(q0, q1, bq, aoff0 + 32, bcol + 32);
            pa1 = f4sum(q0, q1, bq, aoff1 + 32, bcol + 32);
            pw0 = f4sum(k0, k1, bk, woff0 + 32, bcol + 32);
            pw1 = f4sum(k0, k1, bk, woff1 + 32, bcol + 32);
        }
        #pragma unroll
        for (int k = 0; k < 32; ++k) {
            const float4 a = *(const float4*)&As[cur][k][tm*4];
            const float4 b = *(const float4*)&Ws[cur][k][tn*4];
            FMA16(a, b)
        }
    }

    float* C = logits + (long)z * SS * SS;
    #pragma unroll
    for (int i = 0; i < 4; ++i) {
        float4 r;
        r.x = acc[i][0] * 0.125f;
        r.y = acc[i][1] * 0.125f;
        r.z = acc[i][2] * 0.125f;
        r.w = acc[i][3] * 0.125f;
        *(float4*)(C + (long)(m0 + tm*4 + i) * SS + n0 + tn * 4) = r;
    }
}

// ---------------------------------------------------------------------------
// FUSED attn_post + edge_attr (R8 structure, single row/block) + ONE change:
// all 24 logit loads issued upfront into registers (breaks the serialized
// load->reduce->load chain R9's VGPR_Count=40 revealed).
// ---------------------------------------------------------------------------
__global__ __launch_bounds__(256) void attn_edge(
    const float* __restrict__ logits,  // [B][NHEADS][SS][SS]
    const int*   __restrict__ mask,    // [B][SS]
    const float* __restrict__ We, const float* __restrict__ be,
    float* __restrict__ ei,            // [2][ETOT] (float-encoded ints)
    float* __restrict__ ea)            // [ETOT][HH]
{
    const int row = blockIdx.x;        // 0..1023
    const int b   = row >> 9;
    const int qi  = row & 511;
    const int t   = threadIdx.x;
    const int wid = t >> 6, lane = t & 63;

    __shared__ float red[NHEADS][4];
    __shared__ unsigned long long keys[SS];   // 4 KB
    __shared__ float4 wt[192], bt[192];       // 6 KB
    __shared__ unsigned long long mskS[8];
    __shared__ float ssel[KTOP];              // 1 KB

    // stage We col 0 / be early; consumed only after barriers B2/B3
    if (t < 192) {
        float4 w;
        w.x = We[(long)(4 * t + 0) * HH];
        w.y = We[(long)(4 * t + 1) * HH];
        w.z = We[(long)(4 * t + 2) * HH];
        w.w = We[(long)(4 * t + 3) * HH];
        wt[t] = w;
        bt[t] = *(const float4*)(be + 4 * t);
    }

    const bool m0 = mask[b * SS + t] != 0;
    const bool m1 = mask[b * SS + t + 256] != 0;

    const float* basep = logits + ((long)b * NHEADS * SS + qi) * SS;

    // ---- all 24 loads upfront: independent, in flight together ----
    float x0[NHEADS], x1[NHEADS];
    #pragma unroll
    for (int h = 0; h < NHEADS; ++h) {
        const float* lr = basep + (long)h * SS * SS;
        x0[h] = lr[t];
        x1[h] = lr[t + 256];
    }

    // ---- exp + per-head wave reduce, one barrier ----
    #pragma unroll
    for (int h = 0; h < NHEADS; ++h) {
        x0[h] = m0 ? __expf(x0[h]) : 0.f;   // masked -> 0 (== exp(-1e9))
        x1[h] = m1 ? __expf(x1[h]) : 0.f;
        float s = x0[h] + x1[h];
        #pragma unroll
        for (int o = 32; o >= 1; o >>= 1) s += __shfl_xor(s, o);
        if (lane == 0) red[h][wid] = s;
    }
    __syncthreads();                                       // B1

    float a0 = 0.f, a1 = 0.f;
    #pragma unroll
    for (int h = 0; h < NHEADS; ++h) {
        const float rs = 1.0f / (red[h][0] + red[h][1] + red[h][2] + red[h][3]);
        a0 = fmaf(x0[h], rs, a0);
        a1 = fmaf(x1[h], rs, a1);
    }
    a0 *= (1.f / NHEADS);
    a1 *= (1.f / NHEADS);

    // packed keys: (value bits << 32) | (SS-1-j)  => desc value, asc index
    const unsigned long long k0 =
        ((unsigned long long)__float_as_uint(a0) << 32) | (unsigned)(SS - 1 - t);
    const unsigned long long k1 =
        ((unsigned long long)__float_as_uint(a1) << 32) | (unsigned)(SS - 1 - (t + 256));
    keys[t]       = k0;
    keys[t + 256] = k1;
    __syncthreads();                                       // B2

    int r0 = 0, r1 = 0;
    #pragma unroll 8
    for (int j = 0; j < SS; ++j) {
        const unsigned long long kj = keys[j];
        r0 += (kj > k0);
        r1 += (kj > k1);
    }
    const bool sel0 = (r0 < KTOP);
    const bool sel1 = (r1 < KTOP);

    const unsigned long long mm0 = __ballot(sel0);
    const unsigned long long mm1 = __ballot(sel1);
    if (lane == 0) { mskS[wid] = mm0; mskS[4 + wid] = mm1; }
    __syncthreads();                                       // B3
    int cum[8]; int acc = 0;
    #pragma unroll
    for (int i = 0; i < 8; ++i) { cum[i] = acc; acc += __popcll(mskS[i]); }
    const unsigned long long lt = lane ? ((1ull << lane) - 1ull) : 0ull;
    const int p0 = cum[wid]     + __popcll(mskS[wid]     & lt);
    const int p1 = cum[4 + wid] + __popcll(mskS[4 + wid] & lt);

    const float srcv = (float)(b * SS + qi);
    const long  base_e = (long)row * KTOP;
    if (sel0) {
        ei[base_e + p0]        = srcv;
        ei[ETOT + base_e + p0] = (float)(b * SS + t);
        ssel[p0]               = a0;
    }
    if (sel1) {
        ei[base_e + p1]        = srcv;
        ei[ETOT + base_e + p1] = (float)(b * SS + t + 256);
        ssel[p1]               = a1;
    }
    __syncthreads();                                       // B4

    const int cA = t % 192, cB = (t + 64) % 192, cC = (t + 128) % 192;
    const float4 wA = wt[cA], bA = bt[cA];
    const float4 wB = wt[cB], bB = bt[cB];
    const float4 wC = wt[cC], bC = bt[cC];

    // stream this row's edge_attr slab: 256 edges x 768 floats = 49152 float4
    float4* dst = (float4*)(ea + base_e * HH);
    for (int m = 0; m < 64; ++m) {
        const int e_lo = m * 4;
        {
            const int e = e_lo + (t >= 192 ? 1 : 0);
            const float s = ssel[e];
            float4 r;
            r.x = fmaf(s, wA.x, bA.x); r.y = fmaf(s, wA.y, bA.y);
            r.z = fmaf(s, wA.z, bA.z); r.w = fmaf(s, wA.w, bA.w);
            dst[(3*m + 0) * 256 + t] = r;
        }
        {
            const int e = e_lo + 1 + (t >= 128 ? 1 : 0);
            const float s = ssel[e];
            float4 r;
            r.x = fmaf(s, wB.x, bB.x); r.y = fmaf(s, wB.y, bB.y);
            r.z = fmaf(s, wB.z, bB.z); r.w = fmaf(s, wB.w, bB.w);
            dst[(3*m + 1) * 256 + t] = r;
        }
        {
            const int e = e_lo + 2 + (t >= 64 ? 1 : 0);
            const float s = ssel[e];
            float4 r;
            r.x = fmaf(s, wC.x, bC.x); r.y = fmaf(s, wC.y, bC.y);
            r.z = fmaf(s, wC.z, bC.z); r.w = fmaf(s, wC.w, bC.w);
            dst[(3*m + 2) * 256 + t] = r;
        }
    }
}

extern "C" void kernel_launch(void* const* d_in, const int* in_sizes, int n_in,
                              void* d_out, int out_size, void* d_ws, size_t ws_size,
                              hipStream_t stream)
{
    const float* hidden = (const float*)d_in[0];
    const int*   mask   = (const int*)  d_in[1];
    const float* Wp = (const float*)d_in[2];
    const float* bp = (const float*)d_in[3];
    const float* Wq = (const float*)d_in[4];
    const float* bq = (const float*)d_in[5];
    const float* Wk = (const float*)d_in[6];
    const float* bk = (const float*)d_in[7];
    const float* We = (const float*)d_in[8];
    const float* be = (const float*)d_in[9];
    const float* gamma = (const float*)d_in[10];
    const float* beta  = (const float*)d_in[11];

    float* out = (float*)d_out;
    float* ws  = (float*)d_ws;

    float* logits = ws;                     // 6291456 floats (25.2 MB, proven fits)
    float* pn     = out + EA_OFF;           // proj1 partials [2][1024][768]
    float* qkp    = out + EA_OFF + 2*PSZ;   // q/k partials [4][1024][768]

    const dim3 blk(256);

    gemm_sk1<<<dim3(12, 16, 2), blk, 0, stream>>>(hidden, Wp, pn);
    // z 0..3: q/k partial GEMMs; z == 4: folded LayerNorm
    gemm_sk2<<<dim3(12, 16, 5), blk, 0, stream>>>(pn, bp, Wq, Wk, qkp,
                                                  gamma, beta, out);
    gemm_qk2<<<dim3(8, 8, NB * NHEADS), blk, 0, stream>>>(qkp, bq, bk, logits);
    attn_edge<<<dim3(NB * SS), blk, 0, stream>>>(logits, mask, We, be,
                                                 out + EI_OFF, out + EA_OFF);
}